// Round 1
// baseline (158.299 us; speedup 1.0000x reference)
//
#include <hip/hip_runtime.h>

// One row per 32-lane half-wave; lane k owns columns [4k, 4k+4) as a float4.
// Branch-guarded loads: only the operand(s) the taken branch needs are fetched,
// saving ~20% HBM traffic vs loading c0/c1/inputs unconditionally.
__global__ __launch_bounds__(256) void interp_kernel(
    const int* __restrict__ arities,
    const float* __restrict__ inputs,     // [n, 131]
    const float* __restrict__ children,   // [2, n, 128]
    float* __restrict__ out,              // [n, 128]
    int n)
{
    const int lane = threadIdx.x & 31;          // 0..31 -> float4 index in row
    const int wid  = threadIdx.x >> 5;          // half-wave id within block
    const int rowsPerBlock = blockDim.x >> 5;   // 8 for block=256

    for (int row = blockIdx.x * rowsPerBlock + wid; row < n;
         row += gridDim.x * rowsPerBlock)
    {
        const float* inrow = inputs + (size_t)row * 131;
        const float a = inrow[0];
        const float b = inrow[1];
        const float c = inrow[2];

        const float4* c0p = (const float4*)children + (size_t)row * 32;
        const float4* c1p = (const float4*)children + ((size_t)n + (size_t)row) * 32;

        float4 r;
        if (a > 0.0f) {                              // add branch (~50%)
            float4 x = c0p[lane], y = c1p[lane];
            r = make_float4(x.x + y.x, x.y + y.y, x.z + y.z, x.w + y.w);
        } else if (b > 0.0f) {                       // mul branch (~25%)
            float4 x = c0p[lane], y = c1p[lane];
            r = make_float4(x.x * y.x, x.y * y.y, x.z * y.z, x.w * y.w);
        } else if (c > 0.0f) {                       // neg/sub branch (~12.5%)
            if (arities[row] == 1) {
                float4 x = c0p[lane];
                r = make_float4(-x.x, -x.y, -x.z, -x.w);
            } else {
                float4 x = c0p[lane], y = c1p[lane];
                r = make_float4(x.x - y.x, x.y - y.y, x.z - y.z, x.w - y.w);
            }
        } else {                                     // passthrough (~12.5%)
            // inputs row payload starts at column 3 -> not 16B aligned; scalar loads.
            const float* t = inrow + 3 + lane * 4;
            r = make_float4(t[0], t[1], t[2], t[3]);
        }

        ((float4*)out)[(size_t)row * 32 + lane] = r;
    }
}

extern "C" void kernel_launch(void* const* d_in, const int* in_sizes, int n_in,
                              void* d_out, int out_size, void* d_ws, size_t ws_size,
                              hipStream_t stream) {
    const int*   arities  = (const int*)d_in[0];
    const float* inputs   = (const float*)d_in[1];
    const float* children = (const float*)d_in[2];
    float*       out      = (float*)d_out;

    const int n = in_sizes[0];                 // N = 500000 rows
    const int block = 256;
    const int rowsPerBlock = block / 32;       // 8
    int blocksNeeded = (n + rowsPerBlock - 1) / rowsPerBlock;
    int grid = blocksNeeded < 2048 ? blocksNeeded : 2048;  // 2048*4 waves = full CU capacity

    interp_kernel<<<grid, block, 0, stream>>>(arities, inputs, children, out, n);
}